// Round 12
// baseline (491.544 us; speedup 1.0000x reference)
//
#include <hip/hip_runtime.h>
#include <math.h>

// ---------------------------------------------------------------------------
// XLSTMCell: gates = [x|h] @ W + b  (16384 x 5120 x 2048 GEMM, bf16 MFMA)
// R12: max-fidelity m201 discipline on the proven R5 skeleton.
//   - Deep prefetch: stage P1:B0'(kt+1) P2:B1'(kt+1) P3:A1'(kt+1) P4:A0(kt+2)
//     (4-5 phase stage->read lead, 2 LDS slots suffice: every overwrite is
//     >=6 barriers after the unit's last read)
//   - TWO counted waits per K-tile (m201/T4): vmcnt(6) end-P2, vmcnt(4)
//     end-P4. FIFO induction (2 loads/stage, steady state):
//       enter P1(kt): outstanding {A1(kt),A0(kt+1)} = 4
//       P1 +B0'(6): reads A0(kt),B0(kt) [forced by W4(kt-1)]
//       P2 +B1'(8): reads B1(kt) [forced by W4(kt-1)]; W2=vmcnt(6) forces
//         A1(kt) -> P3's read
//       P3 +A1'(8): reads A1(kt)
//       P4 +A0''(10): W4=vmcnt(4) leaves {A1(kt+1),A0(kt+2)}, forces
//         A0(kt+1),B0(kt+1),B1(kt+1) -> next P1/P2 reads
//   - MINIMAL fencing (m141 lesson): plain s_barrier everywhere; the waits'
//     "memory" clobbers order all memory ops (gload_lds/ds_read are memory
//     ops and cannot cross them -> FIFO audit robust); sched_barrier(0) ONLY
//     (a) after lgkmcnt(0) (rule 18, MFMA hoist) and (b) after the two
//     wait-carrying closing barriers (cross-wave read-hoist hazard).
// Pre-swizzled global + linear global_load_lds (offset arg MUST be 0 - the
// builtin's imm offset shifts BOTH addresses, R6-R8 root cause) + XOR'd
// ds_read = 0 bank conflicts (verified R4/R5/R11).
// ws layout: A_bf16[16384][2048] | Wt_bf16[5120][2048] | gates[16384][5120]
// ---------------------------------------------------------------------------

typedef unsigned short u16;
typedef unsigned int   u32;
typedef short  short8 __attribute__((ext_vector_type(8)));
typedef float  f32x4  __attribute__((ext_vector_type(4)));
typedef u16    u16x4  __attribute__((ext_vector_type(4)));
typedef u32    u32x4  __attribute__((ext_vector_type(4)));

#define B_ROWS 16384
#define K_DIM  2048
#define N_DIM  5120
#define H_DIM  1024

__device__ __forceinline__ float b2f(u16 u) {
    u32 v = ((u32)u) << 16;
    return __uint_as_float(v);
}
__device__ __forceinline__ u16 f2b(float f) {   // round-to-nearest-even
    u32 x = __float_as_uint(f);
    u32 r = (x + 0x7fffu + ((x >> 16) & 1u)) >> 16;
    return (u16)r;
}
__device__ __forceinline__ float sigm(float v) {
    return 1.f / (1.f + __expf(-v));
}
__device__ __forceinline__ float tanh_fast(float v) {
    v = fminf(fmaxf(v, -15.f), 15.f);
    float e = __expf(-2.f * v);
    return (1.f - e) / (1.f + e);
}

// ---------------------------------------------------------------------------
// 1) pack [x | h_prev] -> bf16 A [16384][2048], PRE-SWIZZLED:
//    granule slot s of each 64-elem K-window of row r holds granule s^(r&7).
// ---------------------------------------------------------------------------
__global__ __launch_bounds__(256) void convert_A(const float* __restrict__ x,
                                                 const float* __restrict__ h,
                                                 u16* __restrict__ A) {
    size_t idx = ((size_t)blockIdx.x * 256 + threadIdx.x) * 8;   // out elem idx
    int row = (int)(idx >> 11);
    int col = (int)(idx & 2047);                 // granule-aligned (col%8==0)
    int srcCol = (col & ~63) | (((((col >> 3) & 7) ^ (row & 7))) << 3);
    const float* src = (srcCol < 1024) ? (x + (size_t)row * 1024 + srcCol)
                                       : (h + (size_t)row * 1024 + (srcCol - 1024));
    f32x4 v0 = *(const f32x4*)src;
    f32x4 v1 = *(const f32x4*)(src + 4);
    u32x4 w;
    w.x = (u32)f2b(v0.x) | ((u32)f2b(v0.y) << 16);
    w.y = (u32)f2b(v0.z) | ((u32)f2b(v0.w) << 16);
    w.z = (u32)f2b(v1.x) | ((u32)f2b(v1.y) << 16);
    w.w = (u32)f2b(v1.z) | ((u32)f2b(v1.w) << 16);
    *(u32x4*)(A + idx) = w;
}

// ---------------------------------------------------------------------------
// 2) W [2048][5120] f32 -> Wt [5120][2048] bf16, transposed + PRE-SWIZZLED
//    (same granule rule, keyed by n-row & 7).
// ---------------------------------------------------------------------------
__global__ __launch_bounds__(256) void convert_W(const float* __restrict__ W,
                                                 u16* __restrict__ Wt) {
    __shared__ float tile[64][33];      // [k][n]
    const int t  = threadIdx.x;
    const int tx = t & 31;              // n
    const int ty = t >> 5;              // 0..7 (k)
    const int n0 = blockIdx.x * 32;     // 160 blocks
    const int k0 = blockIdx.y * 64;     // 32 blocks
#pragma unroll
    for (int i = 0; i < 8; ++i)
        tile[ty + 8 * i][tx] = W[(size_t)(k0 + ty + 8 * i) * N_DIM + n0 + tx];
    __syncthreads();
    const int n = t >> 3;               // 0..31
    const int s = t & 7;                // output granule slot
    const int g = s ^ (n & 7);          // source granule ((n0+n)&7 == n&7)
    u32x4 w;
    w.x = (u32)f2b(tile[g * 8 + 0][n]) | ((u32)f2b(tile[g * 8 + 1][n]) << 16);
    w.y = (u32)f2b(tile[g * 8 + 2][n]) | ((u32)f2b(tile[g * 8 + 3][n]) << 16);
    w.z = (u32)f2b(tile[g * 8 + 4][n]) | ((u32)f2b(tile[g * 8 + 5][n]) << 16);
    w.w = (u32)f2b(tile[g * 8 + 6][n]) | ((u32)f2b(tile[g * 8 + 7][n]) << 16);
    *(u32x4*)(Wt + (size_t)(n0 + n) * K_DIM + k0 + s * 8) = w;
}

// ---------------------------------------------------------------------------
// 3) GEMM: 256x256, BK=64, 512 thr (8 waves 2Mx4N), 8-phase deep pipeline.
//    Units (16 KiB): A[s][h] = tile rows bit6==h; B[s][h] = n-rows bit5==h.
//    WAR (all >=6 barriers): B0'(P1,kt) vs B0(kt) read P1(kt): other slot;
//    overwrite of B0(kt) at P1(kt+1) = 8 barriers after read. A0(kt+2)
//    staged P4(kt) overwrites A0(kt), last read P1(kt) = 6 barriers earlier.
// ---------------------------------------------------------------------------
#define BK 64

__device__ __forceinline__ void gld_lds16(const void* g, void* l) {
    __builtin_amdgcn_global_load_lds(
        (const __attribute__((address_space(1))) void*)g,
        (__attribute__((address_space(3))) void*)l, 16, 0, 0);   // offset MUST be 0
}

#define AU(s, h) ((s) * 16384 + (h) * 8192)            // u16 index of A unit
#define BU(s, h) (32768 + (s) * 16384 + (h) * 8192)    // u16 index of B unit

#define SB0()   __builtin_amdgcn_sched_barrier(0)
#define SBAR()  __builtin_amdgcn_s_barrier()
#define LGKM0() do { asm volatile("s_waitcnt lgkmcnt(0)" ::: "memory");       \
                     SB0(); } while (0)
#define VM6()   asm volatile("s_waitcnt vmcnt(6)" ::: "memory")
#define VM4()   asm volatile("s_waitcnt vmcnt(4)" ::: "memory")

__global__ __launch_bounds__(512, 2) void gemm_gates(const u16* __restrict__ A,
                                                     const u16* __restrict__ Bt,
                                                     const float* __restrict__ bias,
                                                     u16* __restrict__ gates) {
    __shared__ u16 lds[65536];            // 128 KiB

    const int t = threadIdx.x;
    // T1: bijective XCD swizzle (nwg = 1280, 1280 % 8 == 0)
    const int bid = blockIdx.x;
    const int swz = (bid & 7) * 160 + (bid >> 3);
    const int m0 = (swz & 63) << 8;       // 64 M-blocks
    const int n0 = (swz >> 6) << 8;       // 20 N-blocks

    const int l   = t & 63;
    const int wid = t >> 6;
    const int wr  = wid >> 2;             // 0/1  (M)
    const int wc  = wid & 3;              // 0..3 (N)
    const int lr  = l & 15;
    const int lh  = l >> 4;
    const int z   = lr & 7;
    const int sA0 = (lh ^ z) * 8;         // sk=0 granule slot offset (u16)

    // staging bases: thread t -> row t>>3, granule t&7 (global pre-swizzled)
    const int tb = t >> 3;                // 0..63
    const u16* aBase = A  + (size_t)(m0 + tb) * K_DIM + (t & 7) * 8;
    const u16* bBase = Bt + (size_t)(n0 + (tb & 31) + (tb >> 5) * 64) * K_DIM
                          + (t & 7) * 8;
    const int dOff = t * 8;               // u16

    f32x4 acc[8][4] = {};
    short8 af0[4][2], af1[4][2], bf0[2][2], bf1[2][2];

#define STAGE_A(s, h, OFF) do {                                               \
    gld_lds16(aBase + (size_t)((h) * 64) * K_DIM + (OFF),                     \
              &lds[AU(s, h) + dOff]);                                         \
    gld_lds16(aBase + (size_t)((h) * 64 + 128) * K_DIM + (OFF),               \
              &lds[AU(s, h) + 4096 + dOff]);                                  \
} while (0)
#define STAGE_B(s, h, OFF) do {                                               \
    gld_lds16(bBase + (size_t)((h) * 32) * K_DIM + (OFF),                     \
              &lds[BU(s, h) + dOff]);                                         \
    gld_lds16(bBase + (size_t)((h) * 32 + 128) * K_DIM + (OFF),               \
              &lds[BU(s, h) + 4096 + dOff]);                                  \
} while (0)

#define RD_AFX(dst, s, q) do {                                                \
    _Pragma("unroll") for (int m = 0; m < 4; ++m) {                           \
        const int u_ = AU(s, q) + (wr * 64 + m * 16 + lr) * 64;               \
        dst[m][0] = *(const short8*)&lds[u_ + sA0];                           \
        dst[m][1] = *(const short8*)&lds[u_ + (sA0 ^ 32)];                    \
    }                                                                         \
} while (0)
#define RD_BF(dst, s, h) do {                                                 \
    _Pragma("unroll") for (int n = 0; n < 2; ++n) {                           \
        const int u_ = BU(s, h) + (wc * 32 + n * 16 + lr) * 64;               \
        dst[n][0] = *(const short8*)&lds[u_ + sA0];                           \
        dst[n][1] = *(const short8*)&lds[u_ + (sA0 ^ 32)];                    \
    }                                                                         \
} while (0)

#define MFMA16(AF, q, nh, BF) do {                                            \
    __builtin_amdgcn_s_setprio(1);                                            \
    _Pragma("unroll") for (int sk = 0; sk < 2; ++sk)                          \
    _Pragma("unroll") for (int m = 0; m < 4; ++m)                             \
    _Pragma("unroll") for (int n = 0; n < 2; ++n)                             \
        acc[(q) * 4 + m][(nh) * 2 + n] =                                      \
            __builtin_amdgcn_mfma_f32_16x16x32_bf16(                          \
                AF[m][sk], BF[n][sk], acc[(q) * 4 + m][(nh) * 2 + n], 0, 0, 0);\
    __builtin_amdgcn_s_setprio(0);                                            \
} while (0)

    // prologue: FIFO [A0(0),B0(0),B1(0),A1(0),A0(1)]; vmcnt(4) leaves
    // {A1(0),A0(1)} = steady-state invariant; barrier+SB0 (cross-wave).
    STAGE_A(0, 0, 0); STAGE_B(0, 0, 0); STAGE_B(0, 1, 0); STAGE_A(0, 1, 0);
    STAGE_A(1, 0, BK);
    VM4();
    SBAR(); SB0();

#pragma unroll 1
    for (int kt = 0; kt < 32; ++kt) {
        const int s  = kt & 1;
        const int sp = s ^ 1;
        const int OFF1 = (kt + 1) * BK;   // kt=31: benign in-ws OOB, never read
        const int OFF2 = (kt + 2) * BK;
        // P1: read A0(kt),B0(kt); stage B0(kt+1)
        RD_AFX(af0, s, 0); RD_BF(bf0, s, 0); STAGE_B(sp, 0, OFF1);
        SBAR(); LGKM0(); MFMA16(af0, 0, 0, bf0);
        SBAR();
        // P2: read B1(kt); stage B1(kt+1); W2
        RD_BF(bf1, s, 1); STAGE_B(sp, 1, OFF1);
        SBAR(); LGKM0(); MFMA16(af0, 0, 1, bf1);
        VM6();
        SBAR(); SB0();
        // P3: read A1(kt); stage A1(kt+1)
        RD_AFX(af1, s, 1); STAGE_A(sp, 1, OFF1);
        SBAR(); LGKM0(); MFMA16(af1, 1, 1, bf1);
        SBAR();
        // P4: stage A0(kt+2) into slot s; W4
        STAGE_A(s, 0, OFF2);
        SBAR(); MFMA16(af1, 1, 0, bf0);
        VM4();
        SBAR(); SB0();
    }
#undef STAGE_A
#undef STAGE_B

    asm volatile("s_waitcnt vmcnt(0)" ::: "memory");   // drain garbage stages

    // epilogue: bias + activation (scalar form; block's N-tile in 1 group)
    const int grp = n0 >> 10;             // 0..4 : f,i,o,c,m
#pragma unroll
    for (int ni = 0; ni < 4; ++ni) {
        int col = n0 + wc * 64 + ni * 16 + lr;
        float bv = bias[col];
#pragma unroll
        for (int q = 0; q < 2; ++q) {
#pragma unroll
            for (int m = 0; m < 4; ++m) {
#pragma unroll
                for (int j = 0; j < 4; ++j) {
                    int row = m0 + wr * 128 + q * 64 + m * 16 + lh * 4 + j;
                    float v = acc[q * 4 + m][ni][j] + bv;
                    float g = (grp == 3) ? tanh_fast(v) : sigm(v);
                    gates[(size_t)row * N_DIM + col] = f2b(g);
                }
            }
        }
    }
#undef RD_AFX
#undef RD_BF
#undef MFMA16
}

// ---------------------------------------------------------------------------
// 4) per-row: LN stats over o, cell update, outputs
// ---------------------------------------------------------------------------
__global__ __launch_bounds__(256) void fuse_out(const u16* __restrict__ gates,
                                                const float* __restrict__ c_prev,
                                                const float* __restrict__ ret,
                                                const float* __restrict__ gamma,
                                                const float* __restrict__ beta,
                                                float* __restrict__ out) {
    const int r = blockIdx.x;
    const int t = threadIdx.x;
    const u16* g = gates + (size_t)r * N_DIM;
    const int j0 = t * 4;

    // o = sigmoid(o_pre) already; LN stats over the row of 1024
    u16x4 ov = *(const u16x4*)(g + 2048 + j0);
    float o0 = b2f(ov.x), o1 = b2f(ov.y), o2 = b2f(ov.z), o3 = b2f(ov.w);
    float s1 = o0 + o1 + o2 + o3;
    float s2 = o0 * o0 + o1 * o1 + o2 * o2 + o3 * o3;
#pragma unroll
    for (int off = 32; off; off >>= 1) {
        s1 += __shfl_xor(s1, off, 64);
        s2 += __shfl_xor(s2, off, 64);
    }
    __shared__ float red[8];
    if ((t & 63) == 0) { red[t >> 6] = s1; red[4 + (t >> 6)] = s2; }
    __syncthreads();
    float S1 = red[0] + red[1] + red[2] + red[3];
    float S2 = red[4] + red[5] + red[6] + red[7];
    float mu   = S1 * (1.f / 1024.f);
    float var  = S2 * (1.f / 1024.f) - mu * mu;
    float rstd = rsqrtf(var + 1e-5f);

    u16x4 fv = *(const u16x4*)(g + j0);
    u16x4 iv = *(const u16x4*)(g + 1024 + j0);
    u16x4 cv = *(const u16x4*)(g + 3072 + j0);
    u16x4 mv = *(const u16x4*)(g + 4096 + j0);
    f32x4 cp = *(const f32x4*)(c_prev + (size_t)r * H_DIM + j0);
    f32x4 rt = *(const f32x4*)(ret + j0);
    f32x4 gm = *(const f32x4*)(gamma + j0);
    f32x4 bt = *(const f32x4*)(beta + j0);

    float of[4] = {o0, o1, o2, o3};
    u16 fa[4] = {fv.x, fv.y, fv.z, fv.w};
    u16 ia[4] = {iv.x, iv.y, iv.z, iv.w};
    u16 ca[4] = {cv.x, cv.y, cv.z, cv.w};
    u16 ma[4] = {mv.x, mv.y, mv.z, mv.w};

    f32x4 hout, cout;
#pragma unroll
    for (int i = 0; i < 4; ++i) {
        float f = b2f(fa[i]), ig = b2f(ia[i]), cc = b2f(ca[i]), m = b2f(ma[i]);
        float cpv = cp[i], rv = rt[i];
        float c1 = f * cpv + ig * cc;
        float c2 = c1 * rv + (1.f - rv) * cpv;
        float cn = m * c2 + (1.f - m) * cpv;
        float ln = (of[i] - mu) * rstd * gm[i] + bt[i];
        float oe = sigm(ln);
        float hn = oe * tanh_fast(cn);
        hout[i] = hn;
        cout[i] = cn;
    }
    *(f32x4*)(out + (size_t)r * H_DIM + j0) = hout;
    *(f32x4*)(out + (size_t)B_ROWS * H_DIM + (size_t)r * H_DIM + j0) = cout;
}

// ---------------------------------------------------------------------------
extern "C" void kernel_launch(void* const* d_in, const int* in_sizes, int n_in,
                              void* d_out, int out_size, void* d_ws, size_t ws_size,
                              hipStream_t stream) {
    const float* x      = (const float*)d_in[0];
    const float* h_prev = (const float*)d_in[1];
    const float* c_prev = (const float*)d_in[2];
    const float* W      = (const float*)d_in[3];
    const float* bias   = (const float*)d_in[4];
    const float* gamma  = (const float*)d_in[5];
    const float* beta   = (const float*)d_in[6];
    const float* ret    = (const float*)d_in[7];
    float* out = (float*)d_out;

    u16* Abuf  = (u16*)d_ws;                             // [16384][2048]
    u16* Wt    = Abuf + (size_t)B_ROWS * K_DIM;          // [5120][2048]
    u16* gates = Wt + (size_t)N_DIM * K_DIM;             // [16384][5120]

    convert_A<<<(B_ROWS * K_DIM / 8) / 256, 256, 0, stream>>>(x, h_prev, Abuf);
    convert_W<<<dim3(N_DIM / 32, K_DIM / 64), 256, 0, stream>>>(W, Wt);
    gemm_gates<<<(B_ROWS / 256) * (N_DIM / 256), 512, 0, stream>>>(Abuf, Wt, bias, gates);
    fuse_out<<<B_ROWS, 256, 0, stream>>>(gates, c_prev, ret, gamma, beta, out);
}

// Round 13
// 483.907 us; speedup vs baseline: 1.0158x; 1.0158x over previous
//
#include <hip/hip_runtime.h>
#include <math.h>

// ---------------------------------------------------------------------------
// XLSTMCell: gates = [x|h] @ W + b  (16384 x 5120 x 2048 GEMM, bf16 MFMA)
// R13 = R11 (best: 387-392us GEMM) + two non-schedule levers:
//   (1) L3-friendly XCD blocking: each XCD owns a disjoint 8-M-block slice x
//       all 20 n0 (n outer, m inner). Concurrent working set per XCD =
//       1 MB Wt panel (L2) + 8 MB A slice (L3, fetched once). Bijective:
//       x=m>>3, c=(n<<3)|(m&7). Targets FETCH_SIZE 707 MB -> ~150 MB.
//   (2) K-loop unrolled x2 (16 iters x 2 tiles; R6/R7 bug was 32 iters -
//       triple-checked: 16*2=32 tiles = K2048). Slot s becomes compile-time
//       -> all LDS read/stage offsets fold to base+imm, halving in-loop VALU
//       (VALUBusy 35% = address arithmetic).
// Phase structure, waits (vmcnt(4) at P1..P4 ends), LGKM0 at P1/P2/P3,
// af-pipelining (P4 pre-reads next tile's q0), pre-swizzled global + linear
// global_load_lds (builtin offset arg MUST be 0 - applies to BOTH addresses,
// R6-R8 root cause) + XOR'd ds_read (0 conflicts, verified R4/R5/R11/R12):
// all unchanged from R11.
// Pre-commit: if GEMM >= 380us, structure is at practical ceiling -> stop.
// ws layout: A_bf16[16384][2048] | Wt_bf16[5120][2048] | gates[16384][5120]
// ---------------------------------------------------------------------------

typedef unsigned short u16;
typedef unsigned int   u32;
typedef short  short8 __attribute__((ext_vector_type(8)));
typedef float  f32x4  __attribute__((ext_vector_type(4)));
typedef u16    u16x4  __attribute__((ext_vector_type(4)));
typedef u32    u32x4  __attribute__((ext_vector_type(4)));

#define B_ROWS 16384
#define K_DIM  2048
#define N_DIM  5120
#define H_DIM  1024

__device__ __forceinline__ float b2f(u16 u) {
    u32 v = ((u32)u) << 16;
    return __uint_as_float(v);
}
__device__ __forceinline__ u16 f2b(float f) {   // round-to-nearest-even
    u32 x = __float_as_uint(f);
    u32 r = (x + 0x7fffu + ((x >> 16) & 1u)) >> 16;
    return (u16)r;
}
__device__ __forceinline__ float sigm(float v) {
    return 1.f / (1.f + __expf(-v));
}
__device__ __forceinline__ float tanh_fast(float v) {
    v = fminf(fmaxf(v, -15.f), 15.f);
    float e = __expf(-2.f * v);
    return (1.f - e) / (1.f + e);
}

// ---------------------------------------------------------------------------
// 1) pack [x | h_prev] -> bf16 A [16384][2048], PRE-SWIZZLED:
//    granule slot s of each 64-elem K-window of row r holds granule s^(r&7).
// ---------------------------------------------------------------------------
__global__ __launch_bounds__(256) void convert_A(const float* __restrict__ x,
                                                 const float* __restrict__ h,
                                                 u16* __restrict__ A) {
    size_t idx = ((size_t)blockIdx.x * 256 + threadIdx.x) * 8;   // out elem idx
    int row = (int)(idx >> 11);
    int col = (int)(idx & 2047);                 // granule-aligned (col%8==0)
    int srcCol = (col & ~63) | (((((col >> 3) & 7) ^ (row & 7))) << 3);
    const float* src = (srcCol < 1024) ? (x + (size_t)row * 1024 + srcCol)
                                       : (h + (size_t)row * 1024 + (srcCol - 1024));
    f32x4 v0 = *(const f32x4*)src;
    f32x4 v1 = *(const f32x4*)(src + 4);
    u32x4 w;
    w.x = (u32)f2b(v0.x) | ((u32)f2b(v0.y) << 16);
    w.y = (u32)f2b(v0.z) | ((u32)f2b(v0.w) << 16);
    w.z = (u32)f2b(v1.x) | ((u32)f2b(v1.y) << 16);
    w.w = (u32)f2b(v1.z) | ((u32)f2b(v1.w) << 16);
    *(u32x4*)(A + idx) = w;
}

// ---------------------------------------------------------------------------
// 2) W [2048][5120] f32 -> Wt [5120][2048] bf16, transposed + PRE-SWIZZLED
//    (same granule rule, keyed by n-row & 7).
// ---------------------------------------------------------------------------
__global__ __launch_bounds__(256) void convert_W(const float* __restrict__ W,
                                                 u16* __restrict__ Wt) {
    __shared__ float tile[64][33];      // [k][n]
    const int t  = threadIdx.x;
    const int tx = t & 31;              // n
    const int ty = t >> 5;              // 0..7 (k)
    const int n0 = blockIdx.x * 32;     // 160 blocks
    const int k0 = blockIdx.y * 64;     // 32 blocks
#pragma unroll
    for (int i = 0; i < 8; ++i)
        tile[ty + 8 * i][tx] = W[(size_t)(k0 + ty + 8 * i) * N_DIM + n0 + tx];
    __syncthreads();
    const int n = t >> 3;               // 0..31
    const int s = t & 7;                // output granule slot
    const int g = s ^ (n & 7);          // source granule ((n0+n)&7 == n&7)
    u32x4 w;
    w.x = (u32)f2b(tile[g * 8 + 0][n]) | ((u32)f2b(tile[g * 8 + 1][n]) << 16);
    w.y = (u32)f2b(tile[g * 8 + 2][n]) | ((u32)f2b(tile[g * 8 + 3][n]) << 16);
    w.z = (u32)f2b(tile[g * 8 + 4][n]) | ((u32)f2b(tile[g * 8 + 5][n]) << 16);
    w.w = (u32)f2b(tile[g * 8 + 6][n]) | ((u32)f2b(tile[g * 8 + 7][n]) << 16);
    *(u32x4*)(Wt + (size_t)(n0 + n) * K_DIM + k0 + s * 8) = w;
}

// ---------------------------------------------------------------------------
// 3) GEMM: 256x256, BK=64, 512 thr (8 waves 2Mx4N), 8-phase pipeline,
//    af-pipelined (R11), K-loop unrolled x2 (compile-time slot).
// ---------------------------------------------------------------------------
#define BK 64

__device__ __forceinline__ void gld_lds16(const void* g, void* l) {
    __builtin_amdgcn_global_load_lds(
        (const __attribute__((address_space(1))) void*)g,
        (__attribute__((address_space(3))) void*)l, 16, 0, 0);   // offset MUST be 0
}

#define AU(s, h) ((s) * 16384 + (h) * 8192)            // u16 index of A unit
#define BU(s, h) (32768 + (s) * 16384 + (h) * 8192)    // u16 index of B unit

#define BAR() do { __builtin_amdgcn_sched_barrier(0);                         \
                   __builtin_amdgcn_s_barrier();                              \
                   __builtin_amdgcn_sched_barrier(0); } while (0)
#define LGKM0() do { asm volatile("s_waitcnt lgkmcnt(0)" ::: "memory");       \
                     __builtin_amdgcn_sched_barrier(0); } while (0)
#define VM4() asm volatile("s_waitcnt vmcnt(4)" ::: "memory")

__global__ __launch_bounds__(512, 2) void gemm_gates(const u16* __restrict__ A,
                                                     const u16* __restrict__ Bt,
                                                     const float* __restrict__ bias,
                                                     u16* __restrict__ gates) {
    __shared__ u16 lds[65536];            // 128 KiB

    const int t = threadIdx.x;
    // L3-friendly XCD blocking: XCD x owns m-blocks 8x..8x+7, all 20 n0.
    // Within the XCD chunk: n outer, m inner (8 consecutive blocks share n0
    // -> Wt panel L2-resident; A slice 8 MB L3-resident, fetched once).
    const int bid = blockIdx.x;           // nwg = 1280
    const int xcd = bid & 7;
    const int c   = bid >> 3;             // 0..159
    const int m0 = ((xcd << 3) | (c & 7)) << 8;   // 64 M-blocks
    const int n0 = (c >> 3) << 8;                 // 20 N-blocks

    const int l   = t & 63;
    const int wid = t >> 6;
    const int wr  = wid >> 2;             // 0/1  (M)
    const int wc  = wid & 3;              // 0..3 (N)
    const int lr  = l & 15;
    const int lh  = l >> 4;
    const int z   = lr & 7;
    const int sA0 = (lh ^ z) * 8;         // sk=0 granule slot offset (u16)

    // staging bases: thread t -> row t>>3, granule t&7 (global pre-swizzled)
    const int tb = t >> 3;                // 0..63
    const u16* aBase = A  + (size_t)(m0 + tb) * K_DIM + (t & 7) * 8;
    const u16* bBase = Bt + (size_t)(n0 + (tb & 31) + (tb >> 5) * 64) * K_DIM
                          + (t & 7) * 8;
    const int dOff = t * 8;               // u16

    f32x4 acc[8][4] = {};
    short8 afN[4][2], afC[4][2], bf0[2][2], bf1[2][2];

#define STAGE_A(s, h, OFF) do {                                               \
    gld_lds16(aBase + (size_t)((h) * 64) * K_DIM + (OFF),                     \
              &lds[AU(s, h) + dOff]);                                         \
    gld_lds16(aBase + (size_t)((h) * 64 + 128) * K_DIM + (OFF),               \
              &lds[AU(s, h) + 4096 + dOff]);                                  \
} while (0)
#define STAGE_B(s, h, OFF) do {                                               \
    gld_lds16(bBase + (size_t)((h) * 32) * K_DIM + (OFF),                     \
              &lds[BU(s, h) + dOff]);                                         \
    gld_lds16(bBase + (size_t)((h) * 32 + 128) * K_DIM + (OFF),               \
              &lds[BU(s, h) + 4096 + dOff]);                                  \
} while (0)

#define RD_AFX(dst, s, q) do {                                                \
    _Pragma("unroll") for (int m = 0; m < 4; ++m) {                           \
        const int u_ = AU(s, q) + (wr * 64 + m * 16 + lr) * 64;               \
        dst[m][0] = *(const short8*)&lds[u_ + sA0];                           \
        dst[m][1] = *(const short8*)&lds[u_ + (sA0 ^ 32)];                    \
    }                                                                         \
} while (0)
#define RD_BF(dst, s, h) do {                                                 \
    _Pragma("unroll") for (int n = 0; n < 2; ++n) {                           \
        const int u_ = BU(s, h) + (wc * 32 + n * 16 + lr) * 64;               \
        dst[n][0] = *(const short8*)&lds[u_ + sA0];                           \
        dst[n][1] = *(const short8*)&lds[u_ + (sA0 ^ 32)];                    \
    }                                                                         \
} while (0)

#define MFMA16(AF, q, nh, BF) do {                                            \
    __builtin_amdgcn_s_setprio(1);                                            \
    _Pragma("unroll") for (int sk = 0; sk < 2; ++sk)                          \
    _Pragma("unroll") for (int m = 0; m < 4; ++m)                             \
    _Pragma("unroll") for (int n = 0; n < 2; ++n)                             \
        acc[(q) * 4 + m][(nh) * 2 + n] =                                      \
            __builtin_amdgcn_mfma_f32_16x16x32_bf16(                          \
                AF[m][sk], BF[n][sk], acc[(q) * 4 + m][(nh) * 2 + n], 0, 0, 0);\
    __builtin_amdgcn_s_setprio(0);                                            \
} while (0)

    // One K-tile, compile-time slot s. OFF = stage offset for tile kt+1
    // relative to current aBase/bBase (TILE(0): +64, TILE(1): +128).
    // R11 phase structure verbatim; all waits/FIFO proof unchanged.
#define TILE(s, OFF) do {                                                     \
    /* P1: MFMA q0 x n01 (afN pre-read last P4; bf0 read now) */              \
    RD_BF(bf0, s, 0); STAGE_A((s) ^ 1, 0, OFF);                               \
    BAR(); LGKM0(); MFMA16(afN, 0, 0, bf0); VM4(); BAR();                     \
    /* P2: MFMA q0 x n23 */                                                   \
    RD_BF(bf1, s, 1); STAGE_B((s) ^ 1, 0, OFF);                               \
    BAR(); LGKM0(); MFMA16(afN, 0, 1, bf1); VM4(); BAR();                     \
    /* P3: MFMA q1 x n23 (afC read in-phase) */                               \
    RD_AFX(afC, s, 1); STAGE_B((s) ^ 1, 1, OFF);                              \
    BAR(); LGKM0(); MFMA16(afC, 1, 1, bf1); VM4(); BAR();                     \
    /* P4: pre-read NEXT tile's q0 into afN; no lgkm drain */                 \
    RD_AFX(afN, (s) ^ 1, 0); STAGE_A((s) ^ 1, 1, OFF);                        \
    BAR(); MFMA16(afC, 1, 0, bf0); VM4(); BAR();                              \
} while (0)

    // prologue: stage tile 0 fully, drain, sync, pre-read afN (tile 0 q0).
    STAGE_A(0, 0, 0); STAGE_B(0, 0, 0); STAGE_B(0, 1, 0); STAGE_A(0, 1, 0);
    asm volatile("s_waitcnt vmcnt(0)" ::: "memory");
    BAR();
    RD_AFX(afN, 0, 0);

    // 16 iterations x 2 K-tiles = 32 tiles = K 2048 (R6/R7 bug: 32 iters).
#pragma unroll 1
    for (int it = 0; it < 16; ++it) {
        TILE(0, 64);                      // kt=2it,   stages kt+1
        TILE(1, 128);                     // kt=2it+1, stages kt+2
        aBase += 128;                     // advance 2 K-tiles
        bBase += 128;
    }
    // final TILE(1) staged a garbage "tile 32" (in-ws OOB, never read).
#undef STAGE_A
#undef STAGE_B
#undef TILE

    asm volatile("s_waitcnt vmcnt(0)" ::: "memory");   // drain garbage stages

    // epilogue: bias + activation (scalar form; block's N-tile in 1 group)
    const int grp = n0 >> 10;             // 0..4 : f,i,o,c,m
#pragma unroll
    for (int ni = 0; ni < 4; ++ni) {
        int col = n0 + wc * 64 + ni * 16 + lr;
        float bv = bias[col];
#pragma unroll
        for (int q = 0; q < 2; ++q) {
#pragma unroll
            for (int m = 0; m < 4; ++m) {
#pragma unroll
                for (int j = 0; j < 4; ++j) {
                    int row = m0 + wr * 128 + q * 64 + m * 16 + lh * 4 + j;
                    float v = acc[q * 4 + m][ni][j] + bv;
                    float g = (grp == 3) ? tanh_fast(v) : sigm(v);
                    gates[(size_t)row * N_DIM + col] = f2b(g);
                }
            }
        }
    }
#undef RD_AFX
#undef RD_BF
#undef MFMA16
}

// ---------------------------------------------------------------------------
// 4) per-row: LN stats over o, cell update, outputs
// ---------------------------------------------------------------------------
__global__ __launch_bounds__(256) void fuse_out(const u16* __restrict__ gates,
                                                const float* __restrict__ c_prev,
                                                const float* __restrict__ ret,
                                                const float* __restrict__ gamma,
                                                const float* __restrict__ beta,
                                                float* __restrict__ out) {
    const int r = blockIdx.x;
    const int t = threadIdx.x;
    const u16* g = gates + (size_t)r * N_DIM;
    const int j0 = t * 4;

    // o = sigmoid(o_pre) already; LN stats over the row of 1024
    u16x4 ov = *(const u16x4*)(g + 2048 + j0);
    float o0 = b2f(ov.x), o1 = b2f(ov.y), o2 = b2f(ov.z), o3 = b2f(ov.w);
    float s1 = o0 + o1 + o2 + o3;
    float s2 = o0 * o0 + o1 * o1 + o2 * o2 + o3 * o3;
#pragma unroll
    for (int off = 32; off; off >>= 1) {
        s1 += __shfl_xor(s1, off, 64);
        s2 += __shfl_xor(s2, off, 64);
    }
    __shared__ float red[8];
    if ((t & 63) == 0) { red[t >> 6] = s1; red[4 + (t >> 6)] = s2; }
    __syncthreads();
    float S1 = red[0] + red[1] + red[2] + red[3];
    float S2 = red[4] + red[5] + red[6] + red[7];
    float mu   = S1 * (1.f / 1024.f);
    float var  = S2 * (1.f / 1024.f) - mu * mu;
    float rstd = rsqrtf(var + 1e-5f);

    u16x4 fv = *(const u16x4*)(g + j0);
    u16x4 iv = *(const u16x4*)(g + 1024 + j0);
    u16x4 cv = *(const u16x4*)(g + 3072 + j0);
    u16x4 mv = *(const u16x4*)(g + 4096 + j0);
    f32x4 cp = *(const f32x4*)(c_prev + (size_t)r * H_DIM + j0);
    f32x4 rt = *(const f32x4*)(ret + j0);
    f32x4 gm = *(const f32x4*)(gamma + j0);
    f32x4 bt = *(const f32x4*)(beta + j0);

    float of[4] = {o0, o1, o2, o3};
    u16 fa[4] = {fv.x, fv.y, fv.z, fv.w};
    u16 ia[4] = {iv.x, iv.y, iv.z, iv.w};
    u16 ca[4] = {cv.x, cv.y, cv.z, cv.w};
    u16 ma[4] = {mv.x, mv.y, mv.z, mv.w};

    f32x4 hout, cout;
#pragma unroll
    for (int i = 0; i < 4; ++i) {
        float f = b2f(fa[i]), ig = b2f(ia[i]), cc = b2f(ca[i]), m = b2f(ma[i]);
        float cpv = cp[i], rv = rt[i];
        float c1 = f * cpv + ig * cc;
        float c2 = c1 * rv + (1.f - rv) * cpv;
        float cn = m * c2 + (1.f - m) * cpv;
        float ln = (of[i] - mu) * rstd * gm[i] + bt[i];
        float oe = sigm(ln);
        float hn = oe * tanh_fast(cn);
        hout[i] = hn;
        cout[i] = cn;
    }
    *(f32x4*)(out + (size_t)r * H_DIM + j0) = hout;
    *(f32x4*)(out + (size_t)B_ROWS * H_DIM + (size_t)r * H_DIM + j0) = cout;
}

// ---------------------------------------------------------------------------
extern "C" void kernel_launch(void* const* d_in, const int* in_sizes, int n_in,
                              void* d_out, int out_size, void* d_ws, size_t ws_size,
                              hipStream_t stream) {
    const float* x      = (const float*)d_in[0];
    const float* h_prev = (const float*)d_in[1];
    const float* c_prev = (const float*)d_in[2];
    const float* W      = (const float*)d_in[3];
    const float* bias   = (const float*)d_in[4];
    const float* gamma  = (const float*)d_in[5];
    const float* beta   = (const float*)d_in[6];
    const float* ret    = (const float*)d_in[7];
    float* out = (float*)d_out;

    u16* Abuf  = (u16*)d_ws;                             // [16384][2048]
    u16* Wt    = Abuf + (size_t)B_ROWS * K_DIM;          // [5120][2048]
    u16* gates = Wt + (size_t)N_DIM * K_DIM;             // [16384][5120]

    convert_A<<<(B_ROWS * K_DIM / 8) / 256, 256, 0, stream>>>(x, h_prev, Abuf);
    convert_W<<<dim3(N_DIM / 32, K_DIM / 64), 256, 0, stream>>>(W, Wt);
    gemm_gates<<<(B_ROWS / 256) * (N_DIM / 256), 512, 0, stream>>>(Abuf, Wt, bias, gates);
    fuse_out<<<B_ROWS, 256, 0, stream>>>(gates, c_prev, ret, gamma, beta, out);
}